// Round 9
// baseline (350.100 us; speedup 1.0000x reference)
//
#include <hip/hip_runtime.h>
#include <math.h>

#define D_OUT 16000
#define IN_DIM 2048
#define BATCH 512
#define T2 1024
#define PAD 129   // float2 row stride: 258 banks == 2 mod 32 -> cheap cross-row access

typedef float floatx4 __attribute__((ext_vector_type(4)));  // native vec for NT loads

// ---------- complex helpers ----------
__device__ __forceinline__ float2 cmul(float2 a, float2 b) {
    return make_float2(a.x * b.x - a.y * b.y, a.x * b.y + a.y * b.x);
}
__device__ __forceinline__ float2 cadd(float2 a, float2 b) { return make_float2(a.x + b.x, a.y + b.y); }
__device__ __forceinline__ float2 csub(float2 a, float2 b) { return make_float2(a.x - b.x, a.y - b.y); }
__device__ __forceinline__ float2 cconj(float2 a) { return make_float2(a.x, -a.y); }
__device__ __forceinline__ float2 imul(float2 a) { return make_float2(-a.y, a.x); }  // i*a

__device__ __forceinline__ int PZ(int j, int i) { return j * PAD + i; }

template<int INV>
__device__ __forceinline__ float2 ctw(float2 w) { if (INV) w.y = -w.y; return w; }

// floor(m/125) for m in [0, 15748]
__device__ __forceinline__ int div125(int m) { return (int)(((unsigned)m * 33555u) >> 22); }

// W_16000^m (conj if INV): = W_128^{m/125} * W_16000^{m%125}
template<int INV>
__device__ __forceinline__ float2 bigtw(int m, const float2* w128f, const float2* wNf) {
    int a = div125(m);
    int b = m - a * 125;
    float2 r = cmul(w128f[a], wNf[b]);
    if (INV) r.y = -r.y;
    return r;
}

// conj(W_8000^m) = conj(W_64^{m/125} * W_8000^{m%125}); m <= 7812
__device__ __forceinline__ float2 bigtw8000inv(int m, const float2* w128f, const float2* w8000f) {
    int a = div125(m);
    int b = m - a * 125;
    float2 r = cmul(w128f[2 * a], w8000f[b]);
    return make_float2(r.x, -r.y);
}

// 5-point DFT core (Winograd-style). Forward: omega = e^{-2pi i/5}; INV: conj.
template<int INV>
__device__ __forceinline__ void dft5(float2& b0, float2& b1, float2& b2, float2& b3, float2& b4) {
    const float C1 = 0.30901699437494742f, S1 = 0.95105651629515357f;
    const float C2 = -0.80901699437494745f, S2 = 0.58778525229247314f;
    float2 t1 = cadd(b1, b4), t2 = csub(b1, b4);
    float2 t3 = cadd(b2, b3), t4 = csub(b2, b3);
    float2 X0 = make_float2(b0.x + t1.x + t3.x, b0.y + t1.y + t3.y);
    float2 m1 = make_float2(b0.x + C1 * t1.x + C2 * t3.x, b0.y + C1 * t1.y + C2 * t3.y);
    float2 m2 = make_float2(b0.x + C2 * t1.x + C1 * t3.x, b0.y + C2 * t1.y + C1 * t3.y);
    float2 n1 = make_float2(S1 * t2.x + S2 * t4.x, S1 * t2.y + S2 * t4.y);
    float2 n2 = make_float2(S2 * t2.x - S1 * t4.x, S2 * t2.y - S1 * t4.y);
    if (!INV) {
        b1 = make_float2(m1.x + n1.y, m1.y - n1.x);
        b4 = make_float2(m1.x - n1.y, m1.y + n1.x);
        b2 = make_float2(m2.x + n2.y, m2.y - n2.x);
        b3 = make_float2(m2.x - n2.y, m2.y + n2.x);
    } else {
        b1 = make_float2(m1.x - n1.y, m1.y + n1.x);
        b4 = make_float2(m1.x + n1.y, m1.y - n1.x);
        b2 = make_float2(m2.x - n2.y, m2.y + n2.x);
        b3 = make_float2(m2.x + n2.y, m2.y - n2.x);
    }
    b0 = X0;
}

// ---------------------------------------------------------------------------
// Kernel 1: extract count-sketch (unchanged from round 7: NT loads, 3x5 MLP).
// ---------------------------------------------------------------------------
__global__ void extract_kernel(const float* __restrict__ sk1, const float* __restrict__ sk2,
                               int* __restrict__ h1, float* __restrict__ s1,
                               int* __restrict__ h2, float* __restrict__ s2) {
    int row = blockIdx.x & (IN_DIM - 1);
    bool second = blockIdx.x >= IN_DIM;
    const float* sk = second ? sk2 : sk1;
    const floatx4* base = (const floatx4*)(sk + (size_t)row * D_OUT);
    const int t = threadIdx.x;   // 0..255
    float hacc = 0.f, sacc = 0.f;
    floatx4 v[5];
#pragma unroll
    for (int batch = 0; batch < 3; batch++) {
#pragma unroll
        for (int c = 0; c < 5; c++)
            v[c] = __builtin_nontemporal_load(&base[t + 256 * (5 * batch + c)]);
#pragma unroll
        for (int c = 0; c < 5; c++) {
            float j4 = (float)(4 * (t + 256 * (5 * batch + c)));
            hacc += j4 * fabsf(v[c].x) + (j4 + 1.f) * fabsf(v[c].y) +
                    (j4 + 2.f) * fabsf(v[c].z) + (j4 + 3.f) * fabsf(v[c].w);
            sacc += v[c].x + v[c].y + v[c].z + v[c].w;
        }
    }
    if (t < 160) {
        floatx4 vt = __builtin_nontemporal_load(&base[3840 + t]);
        float j4 = (float)(4 * (3840 + t));
        hacc += j4 * fabsf(vt.x) + (j4 + 1.f) * fabsf(vt.y) +
                (j4 + 2.f) * fabsf(vt.z) + (j4 + 3.f) * fabsf(vt.w);
        sacc += vt.x + vt.y + vt.z + vt.w;
    }
#pragma unroll
    for (int off = 32; off; off >>= 1) {
        hacc += __shfl_down(hacc, off);
        sacc += __shfl_down(sacc, off);
    }
    __shared__ float sh[8];
    int lane = t & 63, wv = t >> 6;
    if (lane == 0) { sh[wv] = hacc; sh[wv + 4] = sacc; }
    __syncthreads();
    if (t == 0) {
        float h = sh[0] + sh[1] + sh[2] + sh[3];
        float s = sh[4] + sh[5] + sh[6] + sh[7];
        int* hh = second ? h2 : h1;
        float* ss = second ? s2 : s1;
        hh[row] = (int)(h + 0.5f);
        ss[row] = s;
    }
}

// Z/C slot for frequency k (k in [0,16000]; 16000 treated as 0)
__device__ __forceinline__ int posk(int k) {
    int k1 = k % 125, k2 = k / 125;
    return PZ(k1, (int)(__brev((unsigned)k2) >> 25));
}

// cross-spectrum from Hermitian-separated packed FFT: G = F1*F2
__device__ __forceinline__ float2 crossG(float2 Zk, float2 Zm) {
    float2 F1 = make_float2(0.5f * (Zk.x + Zm.x), 0.5f * (Zk.y - Zm.y));
    float2 F2 = make_float2(0.5f * (Zk.y + Zm.y), -0.5f * (Zk.x - Zm.x));
    return cmul(F1, F2);
}

// ---------------------------------------------------------------------------
// Kernel 2: per-batch-row CBP.
// Forward: full 16000-pt complex FFT (two real seqs packed); col stages as
//   len=5 pass + merged register-resident radix-25 (len=25+len=125+fold).
// Inverse: half-size 8000-pt IDFT; col stages as merged radix-25
//   (L=125+L=25) + final L=5+epilogue.
// LDS: z[125*129] + pad + w125[125] + w128f[128] + wNf[125] + w8000f[125].
// ---------------------------------------------------------------------------
__global__ void __launch_bounds__(T2, 1) cbp_kernel(
    const float* __restrict__ x1, const float* __restrict__ x2,
    const int* __restrict__ h1, const float* __restrict__ s1,
    const int* __restrict__ h2, const float* __restrict__ s2,
    float* __restrict__ out) {
    __shared__ float2 smem[125 * PAD + 1 + 125 + 128 + 125 + 125];
    float2* z = smem;
    float2* w125 = smem + 125 * PAD + 1;
    float2* w128f = w125 + 125;
    float2* wNf = w128f + 128;
    float2* w8000f = wNf + 125;
    const int tid = threadIdx.x;
    const int b = blockIdx.x;

    // tables + zero z
    for (int t = tid; t < 125; t += T2) {
        float s, c;
        sincospif(t * (2.0f / 125.0f), &s, &c);
        w125[t] = make_float2(c, -s);
        sincospif(t * (1.0f / 8000.0f), &s, &c);
        wNf[t] = make_float2(c, -s);
        sincospif(t * (1.0f / 4000.0f), &s, &c);
        w8000f[t] = make_float2(c, -s);
    }
    for (int a = tid; a < 128; a += T2) {
        float s, c;
        sincospif(a * (1.0f / 64.0f), &s, &c);
        w128f[a] = make_float2(c, -s);
    }
    {
        float4* z4 = (float4*)z;
        for (int i = tid; i < 8063; i += T2) z4[i] = make_float4(0.f, 0.f, 0.f, 0.f);
    }
    __syncthreads();

    // scatter with base-5 digit-reversed j (folds the fwd-col DIT reversal)
    const float* x1r = x1 + (size_t)b * IN_DIM;
    const float* x2r = x2 + (size_t)b * IN_DIM;
    float* zf = (float*)z;
    for (int i = tid; i < IN_DIM; i += T2) {
        int n1 = h1[i] >> 7, n2 = h1[i] & 127;
        int jr = 25 * (n1 % 5) + 5 * ((n1 / 5) % 5) + n1 / 25;
        atomicAdd(&zf[2 * PZ(jr, n2)], x1r[i] * s1[i]);
        n1 = h2[i] >> 7; n2 = h2[i] & 127;
        jr = 25 * (n1 % 5) + 5 * ((n1 / 5) % 5) + n1 / 25;
        atomicAdd(&zf[2 * PZ(jr, n2) + 1], x2r[i] * s2[i]);
    }
    __syncthreads();

    // ---- forward cols pass F1: DIT len=5 (trivial twiddles)
    for (int w = tid; w < 3200; w += T2) {
        int i = w & 127, g = w >> 7;
        int p = PZ(5 * g, i);
        float2 b0 = z[p], b1 = z[p + PAD], b2 = z[p + 2 * PAD], b3 = z[p + 3 * PAD], b4 = z[p + 4 * PAD];
        dft5<0>(b0, b1, b2, b3, b4);
        z[p] = b0; z[p + PAD] = b1; z[p + 2 * PAD] = b2; z[p + 3 * PAD] = b3; z[p + 4 * PAD] = b4;
    }
    __syncthreads();
    // ---- forward cols pass F2: merged len=25 + len=125 + big-twiddle fold.
    // Thread (i, q2): 25 points j = q2 + 5m, m in [0,25).
    if (tid < 640) {
        int i = tid & 127, q2 = tid >> 7;
        float2 r[25];
#pragma unroll
        for (int m = 0; m < 25; m++) r[m] = z[PZ(q2 + 5 * m, i)];
        // len=25 stage: groups m = 5g+t, twiddle W25^{q2 t} = w125[5 q2 t]
#pragma unroll
        for (int g = 0; g < 5; g++) {
            float2 b0 = r[5 * g];
            float2 b1 = cmul(r[5 * g + 1], w125[5 * q2]);
            float2 b2 = cmul(r[5 * g + 2], w125[10 * q2]);
            float2 b3 = cmul(r[5 * g + 3], w125[15 * q2]);
            float2 b4 = cmul(r[5 * g + 4], w125[20 * q2]);
            dft5<0>(b0, b1, b2, b3, b4);
            r[5 * g] = b0; r[5 * g + 1] = b1; r[5 * g + 2] = b2; r[5 * g + 3] = b3; r[5 * g + 4] = b4;
        }
        // len=125 stage: q = q2+5gp, elements m = gp+5t, twiddle W125^{q t};
        // outputs j' = q + 25u with W16000^{i j'} fold.
#pragma unroll
        for (int gp = 0; gp < 5; gp++) {
            int q = q2 + 5 * gp;
            float2 b0 = r[gp];
            float2 b1 = cmul(r[gp + 5],  w125[q]);
            float2 b2 = cmul(r[gp + 10], w125[2 * q]);
            float2 b3 = cmul(r[gp + 15], w125[3 * q]);
            float2 b4 = cmul(r[gp + 20], w125[4 * q]);
            dft5<0>(b0, b1, b2, b3, b4);
            z[PZ(q,       i)] = cmul(b0, bigtw<0>(i * q, w128f, wNf));
            z[PZ(q + 25,  i)] = cmul(b1, bigtw<0>(i * (q + 25), w128f, wNf));
            z[PZ(q + 50,  i)] = cmul(b2, bigtw<0>(i * (q + 50), w128f, wNf));
            z[PZ(q + 75,  i)] = cmul(b3, bigtw<0>(i * (q + 75), w128f, wNf));
            z[PZ(q + 100, i)] = cmul(b4, bigtw<0>(i * (q + 100), w128f, wNf));
        }
    }
    __syncthreads();

    // ---- forward rows: DIF radix-2, natural -> bit-reversed. 2 passes.
    if (tid < 1000) {                           // Pass R1: len=128,64,32,16
        int q = tid / 125, j = tid - q * 125;
        int p = PZ(j, q);
        float2 x[16];
#pragma unroll
        for (int t = 0; t < 16; t++) x[t] = z[p + 8 * t];
#pragma unroll
        for (int t = 0; t < 8; t++) {           // len=128: (t, t+8), W_128^{q+8t}
            float2 u = cadd(x[t], x[t + 8]);
            float2 d = csub(x[t], x[t + 8]);
            x[t + 8] = cmul(d, w128f[q + 8 * t]);
            x[t] = u;
        }
#pragma unroll
        for (int h = 0; h < 16; h += 8)         // len=64
            for (int t = h; t < h + 4; t++) {
                float2 u = cadd(x[t], x[t + 4]);
                float2 d = csub(x[t], x[t + 4]);
                x[t + 4] = cmul(d, w128f[2 * q + 16 * (t & 7)]);
                x[t] = u;
            }
#pragma unroll
        for (int h = 0; h < 16; h += 4)         // len=32
            for (int t = h; t < h + 2; t++) {
                float2 u = cadd(x[t], x[t + 2]);
                float2 d = csub(x[t], x[t + 2]);
                x[t + 2] = cmul(d, w128f[4 * q + 32 * (t & 3)]);
                x[t] = u;
            }
        {
            float2 w16 = w128f[8 * q];          // len=16
#pragma unroll
            for (int t = 0; t < 16; t += 2) {
                float2 u = cadd(x[t], x[t + 1]);
                float2 d = csub(x[t], x[t + 1]);
                x[t + 1] = cmul(d, w16);
                x[t] = u;
            }
        }
#pragma unroll
        for (int t = 0; t < 16; t++) z[p + 8 * t] = x[t];
    }
    __syncthreads();
    // Pass R2: stages len=8,4,2 on contiguous 8-blocks.
    for (int idx = tid; idx < 2000; idx += T2) {
        int g = idx / 125, j = idx - g * 125;
        int p = PZ(j, 8 * g);
        float2 x[8];
#pragma unroll
        for (int d = 0; d < 8; d++) x[d] = z[p + d];
#pragma unroll
        for (int d = 0; d < 4; d++) {           // len=8: (d, d+4), W_8^d
            float2 u = cadd(x[d], x[d + 4]);
            float2 v = csub(x[d], x[d + 4]);
            x[d + 4] = cmul(v, w128f[16 * d]);
            x[d] = u;
        }
#pragma unroll
        for (int h = 0; h < 8; h += 4) {        // len=4
            float2 u = cadd(x[h], x[h + 2]);
            float2 v = csub(x[h], x[h + 2]);
            x[h] = u; x[h + 2] = v;
            u = cadd(x[h + 1], x[h + 3]);
            v = csub(x[h + 1], x[h + 3]);
            x[h + 1] = u;
            x[h + 3] = make_float2(v.y, -v.x);  // * (-i)
        }
#pragma unroll
        for (int d = 0; d < 8; d += 2) {        // len=2
            float2 u = cadd(x[d], x[d + 1]);
            float2 v = csub(x[d], x[d + 1]);
            x[d] = u; x[d + 1] = v;
        }
#pragma unroll
        for (int d = 0; d < 8; d++) z[p + d] = x[d];
    }
    __syncthreads();

    // ---- cross-spectrum + half-spectrum packing.
    for (int k = tid; k <= 4000; k += T2) {
        float2 Zk  = z[posk(k)];
        float2 Zkm = z[posk(k == 0 ? 0 : 16000 - k)];
        float2 Zh  = z[posk(8000 - k)];
        float2 Zhp = z[posk(8000 + k)];
        float2 G1 = crossG(Zk, Zkm);      // G[k]
        float2 G2 = crossG(Zh, Zhp);      // G[8000-k]
        float2 V  = bigtw<1>(k, w128f, wNf);          // e^{+2pi i k/16000}
        float2 V2 = make_float2(-V.x, V.y);           // -conj(V)
        float2 Gc1 = cconj(G1), Gc2 = cconj(G2);
        float2 C1 = cadd(cadd(G1, Gc2), cmul(V,  imul(csub(G1, Gc2))));
        float2 C2 = cadd(cadd(G2, Gc1), cmul(V2, imul(csub(G2, Gc1))));
        z[posk(k)] = C1;
        if (k > 0) z[posk(8000 - k)] = C2;
    }
    __syncthreads();

    // ---- inverse rows: 64-pt IDFT over k2' (data at even i, i6 bit-reversed).
    // Pass A: stages len=2,4,8 on contiguous i6 8-blocks.
    if (tid < 1000) {
        int g = tid / 125, j = tid - g * 125;
        int p = PZ(j, 16 * g);                  // i = 2*(8g + d)
        float2 x[8];
#pragma unroll
        for (int d = 0; d < 8; d++) x[d] = z[p + 2 * d];
#pragma unroll
        for (int d = 0; d < 8; d += 2) {        // len=2
            float2 t = x[d + 1];
            x[d + 1] = csub(x[d], t);
            x[d] = cadd(x[d], t);
        }
#pragma unroll
        for (int h = 0; h < 8; h += 4) {        // len=4: w=1, +i
            float2 t = x[h + 2];
            x[h + 2] = csub(x[h], t);
            x[h] = cadd(x[h], t);
            float2 s = x[h + 3];
            t = make_float2(-s.y, s.x);         // * (+i)
            x[h + 3] = csub(x[h + 1], t);
            x[h + 1] = cadd(x[h + 1], t);
        }
#pragma unroll
        for (int d = 0; d < 4; d++) {           // len=8: conj W_8^d
            float2 t = cmul(ctw<1>(w128f[16 * d]), x[d + 4]);
            x[d + 4] = csub(x[d], t);
            x[d] = cadd(x[d], t);
        }
#pragma unroll
        for (int d = 0; d < 8; d++) z[p + 2 * d] = x[d];
    }
    __syncthreads();
    // Pass B: stages len=16,32,64 (conj) + conj W_8000 big-twiddle fold.
    if (tid < 1000) {
        int q = tid / 125, j = tid - q * 125;
        float2 x[8];
#pragma unroll
        for (int t = 0; t < 8; t++) x[t] = z[PZ(j, 16 * t + 2 * q)];
        {
            float2 w16 = ctw<1>(w128f[8 * q]);  // len=16: (t, t+1)
#pragma unroll
            for (int t = 0; t < 8; t += 2) {
                float2 tt = cmul(w16, x[t + 1]);
                x[t + 1] = csub(x[t], tt);
                x[t] = cadd(x[t], tt);
            }
        }
#pragma unroll
        for (int h = 0; h < 8; h += 4)          // len=32: (t, t+2)
            for (int t = h; t < h + 2; t++) {
                float2 w = ctw<1>(w128f[4 * q + 32 * (t & 1)]);
                float2 tt = cmul(w, x[t + 2]);
                x[t + 2] = csub(x[t], tt);
                x[t] = cadd(x[t], tt);
            }
#pragma unroll
        for (int t = 0; t < 4; t++) {           // len=64: (t, t+4)
            float2 w = ctw<1>(w128f[2 * q + 16 * t]);
            float2 tt = cmul(w, x[t + 4]);
            x[t + 4] = csub(x[t], tt);
            x[t] = cadd(x[t], tt);
        }
#pragma unroll
        for (int t = 0; t < 8; t++)
            z[PZ(j, 16 * t + 2 * q)] = cmul(x[t], bigtw8000inv((q + 8 * t) * j, w128f, w8000f));
    }
    __syncthreads();

    // ---- inverse cols merged: L=125 + L=25 DIF (conj), register-resident.
    // Thread (i6, q2): 25 points j = q2 + 5m over even column 2*i6.
    if (tid < 320) {
        int i6 = tid & 63, q2 = tid >> 6;
        int ii = 2 * i6;
        float2 r[25];
#pragma unroll
        for (int m = 0; m < 25; m++) r[m] = z[PZ(q2 + 5 * m, ii)];
        // L=125: q = q2+5s, elements m = s+5t; output twiddles conj W125^{q u}
#pragma unroll
        for (int s = 0; s < 5; s++) {
            int q = q2 + 5 * s;
            float2 b0 = r[s], b1 = r[s + 5], b2 = r[s + 10], b3 = r[s + 15], b4 = r[s + 20];
            dft5<1>(b0, b1, b2, b3, b4);
            r[s]      = b0;
            r[s + 5]  = cmul(b1, ctw<1>(w125[q]));
            r[s + 10] = cmul(b2, ctw<1>(w125[2 * q]));
            r[s + 15] = cmul(b3, ctw<1>(w125[3 * q]));
            r[s + 20] = cmul(b4, ctw<1>(w125[4 * q]));
        }
        // L=25: elements m = 5u+t; output twiddles conj W25^{q2 t} = w125[5 q2 t]
#pragma unroll
        for (int u = 0; u < 5; u++) {
            float2 b0 = r[5 * u], b1 = r[5 * u + 1], b2 = r[5 * u + 2], b3 = r[5 * u + 3], b4 = r[5 * u + 4];
            dft5<1>(b0, b1, b2, b3, b4);
            r[5 * u]     = b0;
            r[5 * u + 1] = cmul(b1, ctw<1>(w125[5 * q2]));
            r[5 * u + 2] = cmul(b2, ctw<1>(w125[10 * q2]));
            r[5 * u + 3] = cmul(b3, ctw<1>(w125[15 * q2]));
            r[5 * u + 4] = cmul(b4, ctw<1>(w125[20 * q2]));
        }
#pragma unroll
        for (int m = 0; m < 25; m++) z[PZ(q2 + 5 * m, ii)] = r[m];
    }
    __syncthreads();
    // stage L=5 + fused epilogue: w[m] = x[2m]+i*x[2m+1];
    // n1(u) = 25u + 5(g%5) + g/5; out float2 index 64*n1 + i6.
    float2* orow2 = (float2*)(out + (size_t)b * D_OUT);
    for (int w = tid; w < 1600; w += T2) {
        int i6 = w & 63, g = w >> 6;
        int p = PZ(5 * g, 2 * i6);
        float2 b0 = z[p], b1 = z[p + PAD], b2 = z[p + 2 * PAD],
               b3 = z[p + 3 * PAD], b4 = z[p + 4 * PAD];
        dft5<1>(b0, b1, b2, b3, b4);
        int g5 = g % 5, gd = g / 5;
        float2 wv[5] = { b0, b1, b2, b3, b4 };
#pragma unroll
        for (int u = 0; u < 5; u++) {
            int n1 = 25 * u + 5 * g5 + gd;
            float re = wv[u].x, im = wv[u].y;
            float sr = (re > 0.f) ? sqrtf(re) : -sqrtf(-re);
            float si = (im > 0.f) ? sqrtf(im) : -sqrtf(-im);
            orow2[64 * n1 + i6] = make_float2(sr, si);
        }
    }
}

// ---------------------------------------------------------------------------
// Kernel 3: column sum of squares. grid=250, block=512; block owns 64 cols.
// ---------------------------------------------------------------------------
__global__ void colsum_kernel(const float* __restrict__ out, float* __restrict__ colsum) {
    __shared__ float sm[512];
    int c = threadIdx.x & 63, r = threadIdx.x >> 6;
    int col = blockIdx.x * 64 + c;
    float acc = 0.f;
    for (int row = r; row < BATCH; row += 8) {
        float v = out[(size_t)row * D_OUT + col];
        acc += v * v;
    }
    sm[threadIdx.x] = acc;
    __syncthreads();
    if (r == 0) {
        float s = sm[c] + sm[c + 64] + sm[c + 128] + sm[c + 192] +
                  sm[c + 256] + sm[c + 320] + sm[c + 384] + sm[c + 448];
        colsum[col] = s;
    }
}

// ---------------------------------------------------------------------------
// Kernel 4: out[b,n] /= max(sqrt(colsum[n]), 1e-12). float4 vectorized.
// ---------------------------------------------------------------------------
__global__ void normalize_kernel(float* __restrict__ out, const float* __restrict__ colsum) {
    int idx = blockIdx.x * 256 + threadIdx.x;
    float4* o4 = (float4*)out;
    float4 v = o4[idx];
    int n = (idx * 4) % D_OUT;
    const float4 cs = *(const float4*)(colsum + n);
    v.x /= fmaxf(sqrtf(cs.x), 1e-12f);
    v.y /= fmaxf(sqrtf(cs.y), 1e-12f);
    v.z /= fmaxf(sqrtf(cs.z), 1e-12f);
    v.w /= fmaxf(sqrtf(cs.w), 1e-12f);
    o4[idx] = v;
}

extern "C" void kernel_launch(void* const* d_in, const int* in_sizes, int n_in,
                              void* d_out, int out_size, void* d_ws, size_t ws_size,
                              hipStream_t stream) {
    (void)in_sizes; (void)n_in; (void)out_size; (void)ws_size;
    const float* x1 = (const float*)d_in[0];
    const float* x2 = (const float*)d_in[1];
    const float* sk1 = (const float*)d_in[2];
    const float* sk2 = (const float*)d_in[3];
    float* out = (float*)d_out;

    char* ws = (char*)d_ws;
    int* h1 = (int*)(ws);
    float* s1 = (float*)(ws + 8192);
    int* h2 = (int*)(ws + 16384);
    float* s2 = (float*)(ws + 24576);
    float* colsum = (float*)(ws + 32768);   // 16000 floats

    extract_kernel<<<2 * IN_DIM, 256, 0, stream>>>(sk1, sk2, h1, s1, h2, s2);
    cbp_kernel<<<BATCH, T2, 0, stream>>>(x1, x2, h1, s1, h2, s2, out);
    colsum_kernel<<<250, 512, 0, stream>>>(out, colsum);
    normalize_kernel<<<8000, 256, 0, stream>>>(out, colsum);
}

// Round 10
// 345.201 us; speedup vs baseline: 1.0142x; 1.0142x over previous
//
#include <hip/hip_runtime.h>
#include <math.h>

#define D_OUT 16000
#define IN_DIM 2048
#define BATCH 512
#define T2 1024
#define PAD 129   // float2 row stride: 258 banks == 2 mod 32 -> cheap cross-row access

typedef float floatx4 __attribute__((ext_vector_type(4)));  // native vec for NT loads

// ---------- complex helpers ----------
__device__ __forceinline__ float2 cmul(float2 a, float2 b) {
    return make_float2(a.x * b.x - a.y * b.y, a.x * b.y + a.y * b.x);
}
__device__ __forceinline__ float2 cadd(float2 a, float2 b) { return make_float2(a.x + b.x, a.y + b.y); }
__device__ __forceinline__ float2 csub(float2 a, float2 b) { return make_float2(a.x - b.x, a.y - b.y); }
__device__ __forceinline__ float2 cconj(float2 a) { return make_float2(a.x, -a.y); }
__device__ __forceinline__ float2 imul(float2 a) { return make_float2(-a.y, a.x); }  // i*a

__device__ __forceinline__ int PZ(int j, int i) { return j * PAD + i; }

template<int INV>
__device__ __forceinline__ float2 ctw(float2 w) { if (INV) w.y = -w.y; return w; }

// floor(m/125) for m in [0, 15748]
__device__ __forceinline__ int div125(int m) { return (int)(((unsigned)m * 33555u) >> 22); }

// W_16000^m (conj if INV): = W_128^{m/125} * W_16000^{m%125}
template<int INV>
__device__ __forceinline__ float2 bigtw(int m, const float2* w128f, const float2* wNf) {
    int a = div125(m);
    int b = m - a * 125;
    float2 r = cmul(w128f[a], wNf[b]);
    if (INV) r.y = -r.y;
    return r;
}

// conj(W_8000^m) = conj(W_64^{m/125} * W_8000^{m%125}); m <= 7812
__device__ __forceinline__ float2 bigtw8000inv(int m, const float2* w128f, const float2* w8000f) {
    int a = div125(m);
    int b = m - a * 125;
    float2 r = cmul(w128f[2 * a], w8000f[b]);
    return make_float2(r.x, -r.y);
}

// 5-point DFT core (Winograd-style). Forward: omega = e^{-2pi i/5}; INV: conj.
template<int INV>
__device__ __forceinline__ void dft5(float2& b0, float2& b1, float2& b2, float2& b3, float2& b4) {
    const float C1 = 0.30901699437494742f, S1 = 0.95105651629515357f;
    const float C2 = -0.80901699437494745f, S2 = 0.58778525229247314f;
    float2 t1 = cadd(b1, b4), t2 = csub(b1, b4);
    float2 t3 = cadd(b2, b3), t4 = csub(b2, b3);
    float2 X0 = make_float2(b0.x + t1.x + t3.x, b0.y + t1.y + t3.y);
    float2 m1 = make_float2(b0.x + C1 * t1.x + C2 * t3.x, b0.y + C1 * t1.y + C2 * t3.y);
    float2 m2 = make_float2(b0.x + C2 * t1.x + C1 * t3.x, b0.y + C2 * t1.y + C1 * t3.y);
    float2 n1 = make_float2(S1 * t2.x + S2 * t4.x, S1 * t2.y + S2 * t4.y);
    float2 n2 = make_float2(S2 * t2.x - S1 * t4.x, S2 * t2.y - S1 * t4.y);
    if (!INV) {
        b1 = make_float2(m1.x + n1.y, m1.y - n1.x);
        b4 = make_float2(m1.x - n1.y, m1.y + n1.x);
        b2 = make_float2(m2.x + n2.y, m2.y - n2.x);
        b3 = make_float2(m2.x - n2.y, m2.y + n2.x);
    } else {
        b1 = make_float2(m1.x - n1.y, m1.y + n1.x);
        b4 = make_float2(m1.x + n1.y, m1.y - n1.x);
        b2 = make_float2(m2.x - n2.y, m2.y + n2.x);
        b3 = make_float2(m2.x + n2.y, m2.y - n2.x);
    }
    b0 = X0;
}

// ---------------------------------------------------------------------------
// Kernel 1: extract count-sketch (one signed +-1 nonzero per row).
// Branch-free h = sum j*|v|, s = sum v. 256-thread blocks, NT loads,
// 8-deep back-to-back MLP (v[8] = 32 VGPR live; NO launch_bounds cap --
// rounds 5/9 spill lesson). Row = 4000 float4: batch0 c=0..7 (0..2047),
// batch1 c=0..6 (2048..3839), tail t<160 (3840..3999).
// grid = 4096 (2048 rows x 2 sketches).
// ---------------------------------------------------------------------------
__global__ void extract_kernel(const float* __restrict__ sk1, const float* __restrict__ sk2,
                               int* __restrict__ h1, float* __restrict__ s1,
                               int* __restrict__ h2, float* __restrict__ s2) {
    int row = blockIdx.x & (IN_DIM - 1);
    bool second = blockIdx.x >= IN_DIM;
    const float* sk = second ? sk2 : sk1;
    const floatx4* base = (const floatx4*)(sk + (size_t)row * D_OUT);
    const int t = threadIdx.x;   // 0..255
    float hacc = 0.f, sacc = 0.f;
    {
        floatx4 v[8];
#pragma unroll
        for (int c = 0; c < 8; c++)
            v[c] = __builtin_nontemporal_load(&base[t + 256 * c]);
#pragma unroll
        for (int c = 0; c < 8; c++) {
            float j4 = (float)(4 * (t + 256 * c));
            hacc += j4 * fabsf(v[c].x) + (j4 + 1.f) * fabsf(v[c].y) +
                    (j4 + 2.f) * fabsf(v[c].z) + (j4 + 3.f) * fabsf(v[c].w);
            sacc += v[c].x + v[c].y + v[c].z + v[c].w;
        }
#pragma unroll
        for (int c = 0; c < 7; c++)
            v[c] = __builtin_nontemporal_load(&base[t + 256 * (8 + c)]);
        floatx4 vt = (floatx4)(0.f);
        float jt = 0.f;
        if (t < 160) { vt = __builtin_nontemporal_load(&base[3840 + t]); jt = (float)(4 * (3840 + t)); }
#pragma unroll
        for (int c = 0; c < 7; c++) {
            float j4 = (float)(4 * (t + 256 * (8 + c)));
            hacc += j4 * fabsf(v[c].x) + (j4 + 1.f) * fabsf(v[c].y) +
                    (j4 + 2.f) * fabsf(v[c].z) + (j4 + 3.f) * fabsf(v[c].w);
            sacc += v[c].x + v[c].y + v[c].z + v[c].w;
        }
        hacc += jt * fabsf(vt.x) + (jt + 1.f) * fabsf(vt.y) +
                (jt + 2.f) * fabsf(vt.z) + (jt + 3.f) * fabsf(vt.w);
        sacc += vt.x + vt.y + vt.z + vt.w;
    }
#pragma unroll
    for (int off = 32; off; off >>= 1) {
        hacc += __shfl_down(hacc, off);
        sacc += __shfl_down(sacc, off);
    }
    __shared__ float sh[8];
    int lane = t & 63, wv = t >> 6;
    if (lane == 0) { sh[wv] = hacc; sh[wv + 4] = sacc; }
    __syncthreads();
    if (t == 0) {
        float h = sh[0] + sh[1] + sh[2] + sh[3];
        float s = sh[4] + sh[5] + sh[6] + sh[7];
        int* hh = second ? h2 : h1;
        float* ss = second ? s2 : s1;
        hh[row] = (int)(h + 0.5f);
        ss[row] = s;
    }
}

// Z/C slot for frequency k (k in [0,16000]; 16000 treated as 0)
__device__ __forceinline__ int posk(int k) {
    int k1 = k % 125, k2 = k / 125;
    return PZ(k1, (int)(__brev((unsigned)k2) >> 25));
}

// cross-spectrum from Hermitian-separated packed FFT: G = F1*F2
__device__ __forceinline__ float2 crossG(float2 Zk, float2 Zm) {
    float2 F1 = make_float2(0.5f * (Zk.x + Zm.x), 0.5f * (Zk.y - Zm.y));
    float2 F2 = make_float2(0.5f * (Zk.y + Zm.y), -0.5f * (Zk.x - Zm.x));
    return cmul(F1, F2);
}

// ---------------------------------------------------------------------------
// Kernel 2: per-batch-row CBP (round-8 known-good structure; the merged
// radix-25 experiment of round 9 spilled at VGPR=64 and regressed -- reverted).
// Forward: full 16000-pt complex FFT (two real seqs packed).
// Inverse: half-size 8000-pt complex IDFT of packed Hermitian spectrum.
// LDS: z[125*129] + pad + w125[125] + w128f[128] + wNf[125] + w8000f[125].
// ---------------------------------------------------------------------------
__global__ void __launch_bounds__(T2, 1) cbp_kernel(
    const float* __restrict__ x1, const float* __restrict__ x2,
    const int* __restrict__ h1, const float* __restrict__ s1,
    const int* __restrict__ h2, const float* __restrict__ s2,
    float* __restrict__ out) {
    __shared__ float2 smem[125 * PAD + 1 + 125 + 128 + 125 + 125];
    float2* z = smem;
    float2* w125 = smem + 125 * PAD + 1;
    float2* w128f = w125 + 125;
    float2* wNf = w128f + 128;
    float2* w8000f = wNf + 125;
    const int tid = threadIdx.x;
    const int b = blockIdx.x;

    // tables + zero z
    for (int t = tid; t < 125; t += T2) {
        float s, c;
        sincospif(t * (2.0f / 125.0f), &s, &c);
        w125[t] = make_float2(c, -s);
        sincospif(t * (1.0f / 8000.0f), &s, &c);
        wNf[t] = make_float2(c, -s);
        sincospif(t * (1.0f / 4000.0f), &s, &c);
        w8000f[t] = make_float2(c, -s);
    }
    for (int a = tid; a < 128; a += T2) {
        float s, c;
        sincospif(a * (1.0f / 64.0f), &s, &c);
        w128f[a] = make_float2(c, -s);
    }
    {
        float4* z4 = (float4*)z;
        for (int i = tid; i < 8063; i += T2) z4[i] = make_float4(0.f, 0.f, 0.f, 0.f);
    }
    __syncthreads();

    // scatter with base-5 digit-reversed j (folds the fwd-col DIT reversal)
    const float* x1r = x1 + (size_t)b * IN_DIM;
    const float* x2r = x2 + (size_t)b * IN_DIM;
    float* zf = (float*)z;
    for (int i = tid; i < IN_DIM; i += T2) {
        int n1 = h1[i] >> 7, n2 = h1[i] & 127;
        int jr = 25 * (n1 % 5) + 5 * ((n1 / 5) % 5) + n1 / 25;
        atomicAdd(&zf[2 * PZ(jr, n2)], x1r[i] * s1[i]);
        n1 = h2[i] >> 7; n2 = h2[i] & 127;
        jr = 25 * (n1 % 5) + 5 * ((n1 / 5) % 5) + n1 / 25;
        atomicAdd(&zf[2 * PZ(jr, n2) + 1], x2r[i] * s2[i]);
    }
    __syncthreads();

    // ---- forward cols: DIT radix-5, stages len=5,25,125 (input digit-reversed)
    for (int w = tid; w < 3200; w += T2) {      // stage len=5 (trivial twiddles)
        int i = w & 127, g = w >> 7;
        int p = PZ(5 * g, i);
        float2 b0 = z[p], b1 = z[p + PAD], b2 = z[p + 2 * PAD], b3 = z[p + 3 * PAD], b4 = z[p + 4 * PAD];
        dft5<0>(b0, b1, b2, b3, b4);
        z[p] = b0; z[p + PAD] = b1; z[p + 2 * PAD] = b2; z[p + 3 * PAD] = b3; z[p + 4 * PAD] = b4;
    }
    __syncthreads();
    for (int w = tid; w < 3200; w += T2) {      // stage len=25
        int i = w & 127, j5 = w >> 7;
        int g = j5 / 5, q = j5 - 5 * g;
        int p = PZ(g * 25 + q, i);
        float2 b0 = z[p];
        float2 b1 = cmul(z[p + 5 * PAD], w125[q * 5]);
        float2 b2 = cmul(z[p + 10 * PAD], w125[q * 10]);
        float2 b3 = cmul(z[p + 15 * PAD], w125[q * 15]);
        float2 b4 = cmul(z[p + 20 * PAD], w125[q * 20]);
        dft5<0>(b0, b1, b2, b3, b4);
        z[p] = b0; z[p + 5 * PAD] = b1; z[p + 10 * PAD] = b2; z[p + 15 * PAD] = b3; z[p + 20 * PAD] = b4;
    }
    __syncthreads();
    for (int w = tid; w < 3200; w += T2) {      // stage len=125 + big twiddle fold
        int i = w & 127, q = w >> 7;
        int p = PZ(q, i);
        float2 b0 = z[p];
        float2 b1 = cmul(z[p + 25 * PAD], w125[q]);
        float2 b2 = cmul(z[p + 50 * PAD], w125[q * 2]);
        float2 b3 = cmul(z[p + 75 * PAD], w125[q * 3]);
        float2 b4 = cmul(z[p + 100 * PAD], w125[q * 4]);
        dft5<0>(b0, b1, b2, b3, b4);
        z[p]             = cmul(b0, bigtw<0>(i * q, w128f, wNf));
        z[p + 25 * PAD]  = cmul(b1, bigtw<0>(i * (q + 25), w128f, wNf));
        z[p + 50 * PAD]  = cmul(b2, bigtw<0>(i * (q + 50), w128f, wNf));
        z[p + 75 * PAD]  = cmul(b3, bigtw<0>(i * (q + 75), w128f, wNf));
        z[p + 100 * PAD] = cmul(b4, bigtw<0>(i * (q + 100), w128f, wNf));
    }
    __syncthreads();

    // ---- forward rows: DIF radix-2, natural -> bit-reversed. 2 passes.
    if (tid < 1000) {                           // Pass R1: len=128,64,32,16
        int q = tid / 125, j = tid - q * 125;
        int p = PZ(j, q);
        float2 x[16];
#pragma unroll
        for (int t = 0; t < 16; t++) x[t] = z[p + 8 * t];
#pragma unroll
        for (int t = 0; t < 8; t++) {           // len=128: (t, t+8), W_128^{q+8t}
            float2 u = cadd(x[t], x[t + 8]);
            float2 d = csub(x[t], x[t + 8]);
            x[t + 8] = cmul(d, w128f[q + 8 * t]);
            x[t] = u;
        }
#pragma unroll
        for (int h = 0; h < 16; h += 8)         // len=64
            for (int t = h; t < h + 4; t++) {
                float2 u = cadd(x[t], x[t + 4]);
                float2 d = csub(x[t], x[t + 4]);
                x[t + 4] = cmul(d, w128f[2 * q + 16 * (t & 7)]);
                x[t] = u;
            }
#pragma unroll
        for (int h = 0; h < 16; h += 4)         // len=32
            for (int t = h; t < h + 2; t++) {
                float2 u = cadd(x[t], x[t + 2]);
                float2 d = csub(x[t], x[t + 2]);
                x[t + 2] = cmul(d, w128f[4 * q + 32 * (t & 3)]);
                x[t] = u;
            }
        {
            float2 w16 = w128f[8 * q];          // len=16
#pragma unroll
            for (int t = 0; t < 16; t += 2) {
                float2 u = cadd(x[t], x[t + 1]);
                float2 d = csub(x[t], x[t + 1]);
                x[t + 1] = cmul(d, w16);
                x[t] = u;
            }
        }
#pragma unroll
        for (int t = 0; t < 16; t++) z[p + 8 * t] = x[t];
    }
    __syncthreads();
    // Pass R2: stages len=8,4,2 on contiguous 8-blocks.
    for (int idx = tid; idx < 2000; idx += T2) {
        int g = idx / 125, j = idx - g * 125;
        int p = PZ(j, 8 * g);
        float2 x[8];
#pragma unroll
        for (int d = 0; d < 8; d++) x[d] = z[p + d];
#pragma unroll
        for (int d = 0; d < 4; d++) {           // len=8: (d, d+4), W_8^d
            float2 u = cadd(x[d], x[d + 4]);
            float2 v = csub(x[d], x[d + 4]);
            x[d + 4] = cmul(v, w128f[16 * d]);
            x[d] = u;
        }
#pragma unroll
        for (int h = 0; h < 8; h += 4) {        // len=4
            float2 u = cadd(x[h], x[h + 2]);
            float2 v = csub(x[h], x[h + 2]);
            x[h] = u; x[h + 2] = v;
            u = cadd(x[h + 1], x[h + 3]);
            v = csub(x[h + 1], x[h + 3]);
            x[h + 1] = u;
            x[h + 3] = make_float2(v.y, -v.x);  // * (-i)
        }
#pragma unroll
        for (int d = 0; d < 8; d += 2) {        // len=2
            float2 u = cadd(x[d], x[d + 1]);
            float2 v = csub(x[d], x[d + 1]);
            x[d] = u; x[d + 1] = v;
        }
#pragma unroll
        for (int d = 0; d < 8; d++) z[p + d] = x[d];
    }
    __syncthreads();

    // ---- cross-spectrum + half-spectrum packing.
    for (int k = tid; k <= 4000; k += T2) {
        float2 Zk  = z[posk(k)];
        float2 Zkm = z[posk(k == 0 ? 0 : 16000 - k)];
        float2 Zh  = z[posk(8000 - k)];
        float2 Zhp = z[posk(8000 + k)];
        float2 G1 = crossG(Zk, Zkm);      // G[k]
        float2 G2 = crossG(Zh, Zhp);      // G[8000-k]
        float2 V  = bigtw<1>(k, w128f, wNf);          // e^{+2pi i k/16000}
        float2 V2 = make_float2(-V.x, V.y);           // -conj(V)
        float2 Gc1 = cconj(G1), Gc2 = cconj(G2);
        float2 C1 = cadd(cadd(G1, Gc2), cmul(V,  imul(csub(G1, Gc2))));
        float2 C2 = cadd(cadd(G2, Gc1), cmul(V2, imul(csub(G2, Gc1))));
        z[posk(k)] = C1;
        if (k > 0) z[posk(8000 - k)] = C2;
    }
    __syncthreads();

    // ---- inverse rows: 64-pt IDFT over k2' (data at even i, i6 bit-reversed).
    // Pass A: stages len=2,4,8 on contiguous i6 8-blocks.
    if (tid < 1000) {
        int g = tid / 125, j = tid - g * 125;
        int p = PZ(j, 16 * g);                  // i = 2*(8g + d)
        float2 x[8];
#pragma unroll
        for (int d = 0; d < 8; d++) x[d] = z[p + 2 * d];
#pragma unroll
        for (int d = 0; d < 8; d += 2) {        // len=2
            float2 t = x[d + 1];
            x[d + 1] = csub(x[d], t);
            x[d] = cadd(x[d], t);
        }
#pragma unroll
        for (int h = 0; h < 8; h += 4) {        // len=4: w=1, +i
            float2 t = x[h + 2];
            x[h + 2] = csub(x[h], t);
            x[h] = cadd(x[h], t);
            float2 s = x[h + 3];
            t = make_float2(-s.y, s.x);         // * (+i)
            x[h + 3] = csub(x[h + 1], t);
            x[h + 1] = cadd(x[h + 1], t);
        }
#pragma unroll
        for (int d = 0; d < 4; d++) {           // len=8: conj W_8^d
            float2 t = cmul(ctw<1>(w128f[16 * d]), x[d + 4]);
            x[d + 4] = csub(x[d], t);
            x[d] = cadd(x[d], t);
        }
#pragma unroll
        for (int d = 0; d < 8; d++) z[p + 2 * d] = x[d];
    }
    __syncthreads();
    // Pass B: stages len=16,32,64 (conj) + conj W_8000 big-twiddle fold.
    if (tid < 1000) {
        int q = tid / 125, j = tid - q * 125;
        float2 x[8];
#pragma unroll
        for (int t = 0; t < 8; t++) x[t] = z[PZ(j, 16 * t + 2 * q)];
        {
            float2 w16 = ctw<1>(w128f[8 * q]);  // len=16: (t, t+1)
#pragma unroll
            for (int t = 0; t < 8; t += 2) {
                float2 tt = cmul(w16, x[t + 1]);
                x[t + 1] = csub(x[t], tt);
                x[t] = cadd(x[t], tt);
            }
        }
#pragma unroll
        for (int h = 0; h < 8; h += 4)          // len=32: (t, t+2)
            for (int t = h; t < h + 2; t++) {
                float2 w = ctw<1>(w128f[4 * q + 32 * (t & 1)]);
                float2 tt = cmul(w, x[t + 2]);
                x[t + 2] = csub(x[t], tt);
                x[t] = cadd(x[t], tt);
            }
#pragma unroll
        for (int t = 0; t < 4; t++) {           // len=64: (t, t+4)
            float2 w = ctw<1>(w128f[2 * q + 16 * t]);
            float2 tt = cmul(w, x[t + 4]);
            x[t + 4] = csub(x[t], tt);
            x[t] = cadd(x[t], tt);
        }
#pragma unroll
        for (int t = 0; t < 8; t++)
            z[PZ(j, 16 * t + 2 * q)] = cmul(x[t], bigtw8000inv((q + 8 * t) * j, w128f, w8000f));
    }
    __syncthreads();

    // ---- inverse cols: 125-pt DIF (conj) over 64 columns (even i).
    for (int w = tid; w < 1600; w += T2) {      // stage L=125
        int i6 = w & 63, q = w >> 6;
        int p = PZ(q, 2 * i6);
        float2 b0 = z[p], b1 = z[p + 25 * PAD], b2 = z[p + 50 * PAD],
               b3 = z[p + 75 * PAD], b4 = z[p + 100 * PAD];
        dft5<1>(b0, b1, b2, b3, b4);
        z[p]             = b0;
        z[p + 25 * PAD]  = cmul(b1, ctw<1>(w125[q]));
        z[p + 50 * PAD]  = cmul(b2, ctw<1>(w125[2 * q]));
        z[p + 75 * PAD]  = cmul(b3, ctw<1>(w125[3 * q]));
        z[p + 100 * PAD] = cmul(b4, ctw<1>(w125[4 * q]));
    }
    __syncthreads();
    for (int w = tid; w < 1600; w += T2) {      // stage L=25
        int i6 = w & 63, j5 = w >> 6;
        int u1 = j5 / 5, q2 = j5 - 5 * u1;
        int p = PZ(25 * u1 + q2, 2 * i6);
        float2 b0 = z[p], b1 = z[p + 5 * PAD], b2 = z[p + 10 * PAD],
               b3 = z[p + 15 * PAD], b4 = z[p + 20 * PAD];
        dft5<1>(b0, b1, b2, b3, b4);
        z[p]            = b0;
        z[p + 5 * PAD]  = cmul(b1, ctw<1>(w125[5 * q2]));
        z[p + 10 * PAD] = cmul(b2, ctw<1>(w125[10 * q2]));
        z[p + 15 * PAD] = cmul(b3, ctw<1>(w125[15 * q2]));
        z[p + 20 * PAD] = cmul(b4, ctw<1>(w125[20 * q2]));
    }
    __syncthreads();
    // stage L=5 + fused epilogue: w[m] = x[2m]+i*x[2m+1];
    // n1(u) = 25u + 5(g%5) + g/5; out float2 index 64*n1 + i6.
    float2* orow2 = (float2*)(out + (size_t)b * D_OUT);
    for (int w = tid; w < 1600; w += T2) {
        int i6 = w & 63, g = w >> 6;
        int p = PZ(5 * g, 2 * i6);
        float2 b0 = z[p], b1 = z[p + PAD], b2 = z[p + 2 * PAD],
               b3 = z[p + 3 * PAD], b4 = z[p + 4 * PAD];
        dft5<1>(b0, b1, b2, b3, b4);
        int g5 = g % 5, gd = g / 5;
        float2 wv[5] = { b0, b1, b2, b3, b4 };
#pragma unroll
        for (int u = 0; u < 5; u++) {
            int n1 = 25 * u + 5 * g5 + gd;
            float re = wv[u].x, im = wv[u].y;
            float sr = (re > 0.f) ? sqrtf(re) : -sqrtf(-re);
            float si = (im > 0.f) ? sqrtf(im) : -sqrtf(-im);
            orow2[64 * n1 + i6] = make_float2(sr, si);
        }
    }
}

// ---------------------------------------------------------------------------
// Kernel 3: column sum of squares. grid=250, block=512; block owns 64 cols.
// ---------------------------------------------------------------------------
__global__ void colsum_kernel(const float* __restrict__ out, float* __restrict__ colsum) {
    __shared__ float sm[512];
    int c = threadIdx.x & 63, r = threadIdx.x >> 6;
    int col = blockIdx.x * 64 + c;
    float acc = 0.f;
    for (int row = r; row < BATCH; row += 8) {
        float v = out[(size_t)row * D_OUT + col];
        acc += v * v;
    }
    sm[threadIdx.x] = acc;
    __syncthreads();
    if (r == 0) {
        float s = sm[c] + sm[c + 64] + sm[c + 128] + sm[c + 192] +
                  sm[c + 256] + sm[c + 320] + sm[c + 384] + sm[c + 448];
        colsum[col] = s;
    }
}

// ---------------------------------------------------------------------------
// Kernel 4: out[b,n] /= max(sqrt(colsum[n]), 1e-12). float4 vectorized.
// ---------------------------------------------------------------------------
__global__ void normalize_kernel(float* __restrict__ out, const float* __restrict__ colsum) {
    int idx = blockIdx.x * 256 + threadIdx.x;
    float4* o4 = (float4*)out;
    float4 v = o4[idx];
    int n = (idx * 4) % D_OUT;
    const float4 cs = *(const float4*)(colsum + n);
    v.x /= fmaxf(sqrtf(cs.x), 1e-12f);
    v.y /= fmaxf(sqrtf(cs.y), 1e-12f);
    v.z /= fmaxf(sqrtf(cs.z), 1e-12f);
    v.w /= fmaxf(sqrtf(cs.w), 1e-12f);
    o4[idx] = v;
}

extern "C" void kernel_launch(void* const* d_in, const int* in_sizes, int n_in,
                              void* d_out, int out_size, void* d_ws, size_t ws_size,
                              hipStream_t stream) {
    (void)in_sizes; (void)n_in; (void)out_size; (void)ws_size;
    const float* x1 = (const float*)d_in[0];
    const float* x2 = (const float*)d_in[1];
    const float* sk1 = (const float*)d_in[2];
    const float* sk2 = (const float*)d_in[3];
    float* out = (float*)d_out;

    char* ws = (char*)d_ws;
    int* h1 = (int*)(ws);
    float* s1 = (float*)(ws + 8192);
    int* h2 = (int*)(ws + 16384);
    float* s2 = (float*)(ws + 24576);
    float* colsum = (float*)(ws + 32768);   // 16000 floats

    extract_kernel<<<2 * IN_DIM, 256, 0, stream>>>(sk1, sk2, h1, s1, h2, s2);
    cbp_kernel<<<BATCH, T2, 0, stream>>>(x1, x2, h1, s1, h2, s2, out);
    colsum_kernel<<<250, 512, 0, stream>>>(out, colsum);
    normalize_kernel<<<8000, 256, 0, stream>>>(out, colsum);
}